// Round 2
// baseline (476.278 us; speedup 1.0000x reference)
//
#include <hip/hip_runtime.h>
#include <hip/hip_bf16.h>

// RWKV6 single-token self-attention, H=4096, NH=64, HS=64, TM=64, TD=128.
// Dtype-adaptive: k0_detect probes whether buffers are bf16 or fp32 and all
// loads/stores branch (wave-uniformly) on the detected flag.
//
// Kernel chain (stream-ordered):
//  k0 : detect input dtype -> ws[WS_FLAG]
//  k1 : LayerNorm(x) -> xl (output 1), sx, xxx
//  k2a: partial dots for z = tanh(xxx @ maa_w1)   (split-K over 16 blocks)
//  k2c: reduce+tanh z, LoRA up -> mvals[5][4096]
//  k3a: partial dots for dz = tanh(mw @ decay_w1)
//  k3b: reduce+tanh dz, td = exp(-exp(clip(dz @ decay_w2 + time_decay)))
//  k4 : 4 matvecs r,k,v,g (one wave per row, vectorized), silu on g
//  k5 : per-head kv outer, wkv readout, state2 update (output 2),
//       instance-norm + affine + gate -> og
//  k6 : out0 = x + og @ Wo.T (output 0)

#define HDIM 4096
#define NHEAD 64
#define HSZ 64

#define WS_XL    0
#define WS_SX    4096
#define WS_XXX   8192
#define WS_PART  12288   // 16*320
#define WS_DPART 17408   // 16*128
#define WS_MV    20480   // 5*4096: f=0 mw, 1 mk, 2 mv, 3 mr, 4 mg
#define WS_TD    40960
#define WS_R     45056
#define WS_K     49152
#define WS_V     53248
#define WS_G     57344
#define WS_OG    61440
#define WS_FLAG  65536
// total 65537 floats ~= 256 KB of d_ws

typedef unsigned short bfraw;

__device__ __forceinline__ float bf2f(bfraw u) {
    union { unsigned int u; float f; } v; v.u = ((unsigned int)u) << 16; return v.f;
}
__device__ __forceinline__ bfraw f2bf(float f) {
    union { float f; unsigned int u; } v; v.f = f;
    unsigned int u = v.u;
    unsigned int r = (u + 0x7fffu + ((u >> 16) & 1u)) >> 16;  // RNE
    return (bfraw)r;
}
__device__ __forceinline__ float ldin(const void* p, long long i, bool isbf) {
    return isbf ? bf2f(((const bfraw*)p)[i]) : ((const float*)p)[i];
}
__device__ __forceinline__ void stout(void* p, long long i, float v, bool isbf) {
    if (isbf) ((bfraw*)p)[i] = f2bf(v); else ((float*)p)[i] = v;
}
__device__ __forceinline__ float waveReduce(float v) {
    for (int m = 32; m; m >>= 1) v += __shfl_xor(v, m);
    return v;
}

// ---------------- k0: detect dtype of input buffers ----------------------
// x is ~N(0,1). If bf16: slots 0..255 nearly all have sane exponents.
// If fp32-read-as-bf16: even slots are mantissa garbage (~19% sane) ->
// expected sane count ~152 vs 256. Threshold 208.
__global__ __launch_bounds__(64)
void k0_detect(const void* x, float* ws) {
    int lane = threadIdx.x;
    const bfraw* p = (const bfraw*)x;
    int cnt = 0;
    for (int k = 0; k < 4; ++k) {
        bfraw u = p[lane * 4 + k];
        int e = (u >> 7) & 0xFF;
        if (e >= 96 && e <= 144) cnt++;   // |v| in ~[2^-31, 2^17]
    }
    for (int m = 32; m; m >>= 1) cnt += __shfl_xor(cnt, m);
    if (lane == 0) ws[WS_FLAG] = (cnt >= 208) ? 1.0f : 0.0f;
}

// ---------------- k1: layernorm + token-shift mix input ----------------
__global__ __launch_bounds__(256)
void k1_ln_mix(const void* __restrict__ x, const void* __restrict__ st1,
               const void* __restrict__ lnw, const void* __restrict__ lnb,
               const void* __restrict__ tmx, void* __restrict__ dout,
               float* __restrict__ ws) {
    bool isbf = ws[WS_FLAG] != 0.0f;
    int tid = threadIdx.x;
    float xv[16];
    float s1 = 0.f, s2 = 0.f;
    for (int k = 0; k < 16; ++k) {
        float v = ldin(x, tid + k * 256, isbf);
        xv[k] = v; s1 += v; s2 += v * v;
    }
    s1 = waveReduce(s1); s2 = waveReduce(s2);
    __shared__ float red[8];
    int wid = tid >> 6, lane = tid & 63;
    if (lane == 0) { red[wid] = s1; red[4 + wid] = s2; }
    __syncthreads();
    float t1 = red[0] + red[1] + red[2] + red[3];
    float t2 = red[4] + red[5] + red[6] + red[7];
    float mu = t1 * (1.0f / HDIM);
    float var = fmaxf(t2 * (1.0f / HDIM) - mu * mu, 0.0f);
    float rstd = rsqrtf(var + 1e-5f);
    for (int k = 0; k < 16; ++k) {
        int i = tid + k * 256;
        float xl = (xv[k] - mu) * rstd * ldin(lnw, i, isbf) + ldin(lnb, i, isbf);
        float sx = ldin(st1, i, isbf) - xl;
        float xxx = xl + sx * ldin(tmx, i, isbf);
        stout(dout, 4096 + i, xl, isbf);   // output 1: xl
        ws[WS_XL + i] = xl;
        ws[WS_SX + i] = sx;
        ws[WS_XXX + i] = xxx;
    }
}

// ---------------- k2a: split-K partials of xxx @ maa_w1 (4096x320) -------
__global__ __launch_bounds__(320)
void k2a_maa_down(const void* __restrict__ w1, float* __restrict__ ws) {
    bool isbf = ws[WS_FLAG] != 0.0f;
    __shared__ float lx[256];
    int tid = threadIdx.x, b = blockIdx.x;
    if (tid < 256) lx[tid] = ws[WS_XXX + b * 256 + tid];
    __syncthreads();
    float acc = 0.f;
    long long base = (long long)b * 256 * 320 + tid;
    for (int j = 0; j < 256; ++j) acc += lx[j] * ldin(w1, base + (long long)j * 320, isbf);
    ws[WS_PART + b * 320 + tid] = acc;
}

// ---------------- k2c: z=tanh(.), LoRA up, mvals -------------------------
__global__ __launch_bounds__(256)
void k2c_maa_up(const void* __restrict__ w2, const void* __restrict__ tm,
                float* __restrict__ ws) {
    bool isbf = ws[WS_FLAG] != 0.0f;
    int tid = threadIdx.x;
    int f = blockIdx.x >> 4;
    int hb = (blockIdx.x & 15) << 8;
    __shared__ float zl[64];
    if (tid < 64) {
        float s = 0.f;
        for (int b = 0; b < 16; ++b) s += ws[WS_PART + b * 320 + f * 64 + tid];
        zl[tid] = tanhf(s);
    }
    __syncthreads();
    int h = hb + tid;
    float acc = 0.f;
    long long base = (long long)f * 64 * HDIM + h;
    for (int t = 0; t < 64; ++t) acc += zl[t] * ldin(w2, base + (long long)t * HDIM, isbf);
    float mval = ws[WS_XL + h] + ws[WS_SX + h] * (acc + ldin(tm, f * HDIM + h, isbf));
    ws[WS_MV + f * HDIM + h] = mval;
}

// ---------------- k3a: split-K partials of mw @ decay_w1 (4096x128) ------
__global__ __launch_bounds__(128)
void k3a_decay_down(const void* __restrict__ dw1, float* __restrict__ ws) {
    bool isbf = ws[WS_FLAG] != 0.0f;
    __shared__ float lm[256];
    int tid = threadIdx.x, b = blockIdx.x;
    lm[tid]       = ws[WS_MV + b * 256 + tid];        // mw is f=0
    lm[tid + 128] = ws[WS_MV + b * 256 + 128 + tid];
    __syncthreads();
    float acc = 0.f;
    long long base = (long long)b * 256 * 128 + tid;
    for (int j = 0; j < 256; ++j) acc += lm[j] * ldin(dw1, base + (long long)j * 128, isbf);
    ws[WS_DPART + b * 128 + tid] = acc;
}

// ---------------- k3b: dz=tanh(.), td = exp(-exp(clip(...))) -------------
__global__ __launch_bounds__(256)
void k3b_decay_up(const void* __restrict__ dw2, const void* __restrict__ tdec,
                  float* __restrict__ ws) {
    bool isbf = ws[WS_FLAG] != 0.0f;
    int tid = threadIdx.x;
    __shared__ float dz[128];
    if (tid < 128) {
        float s = 0.f;
        for (int b = 0; b < 16; ++b) s += ws[WS_DPART + b * 128 + tid];
        dz[tid] = tanhf(s);
    }
    __syncthreads();
    int i = blockIdx.x * 256 + tid;
    float acc = 0.f;
    for (int t = 0; t < 128; ++t) acc += dz[t] * ldin(dw2, (long long)t * HDIM + i, isbf);
    float tv = acc + ldin(tdec, i, isbf);
    tv = fminf(fmaxf(tv, -9.72f), 2.27f);
    ws[WS_TD + i] = expf(-expf(tv));
}

// ---------------- k4: 4 big matvecs r,k,v,g (one wave per row) -----------
__device__ __forceinline__ float dot_row_dual(const void* __restrict__ W, long long row,
                                              const float* __restrict__ m,
                                              int lane, bool isbf) {
    float acc = 0.f;
    if (isbf) {
        const bfraw* wr = (const bfraw*)W + row * HDIM;
        for (int it = 0; it < 8; ++it) {
            int base = it * 512 + lane * 8;
            uint4 wv = *(const uint4*)(wr + base);
            float4 m0 = *(const float4*)(m + base);
            float4 m1 = *(const float4*)(m + base + 4);
            acc += bf2f((bfraw)(wv.x & 0xffff)) * m0.x + bf2f((bfraw)(wv.x >> 16)) * m0.y;
            acc += bf2f((bfraw)(wv.y & 0xffff)) * m0.z + bf2f((bfraw)(wv.y >> 16)) * m0.w;
            acc += bf2f((bfraw)(wv.z & 0xffff)) * m1.x + bf2f((bfraw)(wv.z >> 16)) * m1.y;
            acc += bf2f((bfraw)(wv.w & 0xffff)) * m1.z + bf2f((bfraw)(wv.w >> 16)) * m1.w;
        }
    } else {
        const float* wr = (const float*)W + row * HDIM;
        for (int it = 0; it < 8; ++it) {
            int base = it * 512 + lane * 8;
            float4 a0 = *(const float4*)(wr + base);
            float4 a1 = *(const float4*)(wr + base + 4);
            float4 m0 = *(const float4*)(m + base);
            float4 m1 = *(const float4*)(m + base + 4);
            acc += a0.x * m0.x + a0.y * m0.y + a0.z * m0.z + a0.w * m0.w;
            acc += a1.x * m1.x + a1.y * m1.y + a1.z * m1.z + a1.w * m1.w;
        }
    }
    return waveReduce(acc);
}

__global__ __launch_bounds__(256)
void k4_matvec4(const void* __restrict__ Wr, const void* __restrict__ Wk,
                const void* __restrict__ Wv, const void* __restrict__ Wg,
                float* __restrict__ ws) {
    bool isbf = ws[WS_FLAG] != 0.0f;
    int tid = threadIdx.x;
    int wave = tid >> 6, lane = tid & 63;
    int gr = blockIdx.x * 4 + wave;      // 0..16383
    int mat = gr >> 12;
    int row = gr & 4095;
    const void* W; const float* m; float* y;
    if (mat == 0)      { W = Wr; m = ws + WS_MV + 3 * HDIM; y = ws + WS_R; }
    else if (mat == 1) { W = Wk; m = ws + WS_MV + 1 * HDIM; y = ws + WS_K; }
    else if (mat == 2) { W = Wv; m = ws + WS_MV + 2 * HDIM; y = ws + WS_V; }
    else               { W = Wg; m = ws + WS_MV + 4 * HDIM; y = ws + WS_G; }
    float acc = dot_row_dual(W, row, m, lane, isbf);
    if (lane == 0) {
        if (mat == 3) acc = acc / (1.0f + expf(-acc));   // silu
        y[row] = acc;
    }
}

// ---------------- k5: per-head state update + readout + IN + gate --------
__global__ __launch_bounds__(64)
void k5_heads(const void* __restrict__ state2, const void* __restrict__ tfirst,
              const void* __restrict__ lnxw, const void* __restrict__ lnxb,
              void* __restrict__ dout, float* __restrict__ ws) {
    bool isbf = ws[WS_FLAG] != 0.0f;
    int h = blockIdx.x, j = threadIdx.x;
    int gi = h * 64 + j;
    float rj = ws[WS_R + gi], kj = ws[WS_K + gi], vj = ws[WS_V + gi];
    float tdj = ws[WS_TD + gi];
    float tfj = ldin(tfirst, gi, isbf);
    __shared__ float lr[64], lk[64], ltd[64];
    lr[j] = rj; lk[j] = kj; ltd[j] = tdj;
    float c = waveReduce(rj * kj * tfj);   // sum_i r_i k_i tf_i
    __syncthreads();
    float acc = 0.f;
    long long sbase = (long long)h * 4096 + j;
    for (int i = 0; i < 64; ++i) {
        float s = ldin(state2, sbase + i * 64, isbf);
        acc += lr[i] * s;                                            // r @ state2 part
        stout(dout, 8192 + sbase + i * 64, lk[i] * vj + s * ltd[i], isbf);  // output 2
    }
    float oh = vj * c + acc;                            // r @ (kv*tf + s)
    float s1 = waveReduce(oh);
    float s2 = waveReduce(oh * oh);
    float mu = s1 * (1.0f / 64.0f);
    float var = fmaxf(s2 * (1.0f / 64.0f) - mu * mu, 0.0f);
    float rstd = rsqrtf(var + 1e-5f);
    float o = (oh - mu) * rstd * ldin(lnxw, gi, isbf) + ldin(lnxb, gi, isbf);
    ws[WS_OG + gi] = o * ws[WS_G + gi];
}

// ---------------- k6: out0 = x + og @ Wo.T -------------------------------
__global__ __launch_bounds__(256)
void k6_out(const void* __restrict__ Wo, const void* __restrict__ x,
            void* __restrict__ dout, float* __restrict__ ws) {
    bool isbf = ws[WS_FLAG] != 0.0f;
    int tid = threadIdx.x;
    int wave = tid >> 6, lane = tid & 63;
    int row = blockIdx.x * 4 + wave;
    float acc = dot_row_dual(Wo, row, ws + WS_OG, lane, isbf);
    if (lane == 0) stout(dout, row, ldin(x, row, isbf) + acc, isbf);
}

extern "C" void kernel_launch(void* const* d_in, const int* in_sizes, int n_in,
                              void* d_out, int out_size, void* d_ws, size_t ws_size,
                              hipStream_t stream) {
    const void* x      = d_in[0];
    const void* st1    = d_in[1];
    const void* st2    = d_in[2];
    const void* ln1w   = d_in[3];
    const void* ln1b   = d_in[4];
    const void* tmx    = d_in[5];
    const void* tmaa   = d_in[6];
    const void* maw1   = d_in[7];
    const void* maw2   = d_in[8];
    const void* tdec   = d_in[9];
    const void* tfirst = d_in[10];
    const void* dw1    = d_in[11];
    const void* dw2    = d_in[12];
    const void* Wr     = d_in[13];
    const void* Wk     = d_in[14];
    const void* Wv     = d_in[15];
    const void* Wg     = d_in[16];
    const void* Wo     = d_in[17];
    const void* lnxw   = d_in[18];
    const void* lnxb   = d_in[19];

    float* ws = (float*)d_ws;

    k0_detect<<<1, 64, 0, stream>>>(x, ws);
    k1_ln_mix<<<1, 256, 0, stream>>>(x, st1, ln1w, ln1b, tmx, d_out, ws);
    k2a_maa_down<<<16, 320, 0, stream>>>(maw1, ws);
    k2c_maa_up<<<80, 256, 0, stream>>>(maw2, tmaa, ws);
    k3a_decay_down<<<16, 128, 0, stream>>>(dw1, ws);
    k3b_decay_up<<<16, 256, 0, stream>>>(dw2, tdec, ws);
    k4_matvec4<<<4096, 256, 0, stream>>>(Wr, Wk, Wv, Wg, ws);
    k5_heads<<<64, 64, 0, stream>>>(st2, tfirst, lnxw, lnxb, d_out, ws);
    k6_out<<<1024, 256, 0, stream>>>(Wo, x, d_out, ws);
}

// Round 5
// 434.827 us; speedup vs baseline: 1.0953x; 1.0953x over previous
//
#include <hip/hip_runtime.h>
#include <hip/hip_bf16.h>

// RWKV6 single-token self-attention, H=4096, NH=64, HS=64, TM=64, TD=128.
// Dtype-adaptive (R2-proven): k0_detect probes bf16 vs fp32; all loads/stores
// branch wave-uniformly on the flag. R5 = R2 structure + inner-loop unrolls.
//
// Kernel chain (stream-ordered):
//  k0 : detect input dtype -> ws[WS_FLAG]
//  k1 : LayerNorm(x) -> xl (output 1), sx, xxx
//  k2a: partial dots for z = tanh(xxx @ maa_w1)   (split-K over 16 blocks)
//  k2c: reduce+tanh z, LoRA up -> mvals[5][4096]
//  k3a: partial dots for dz = tanh(mw @ decay_w1)
//  k3b: reduce+tanh dz, td = exp(-exp(clip(dz @ decay_w2 + time_decay)))
//  k4 : 4 matvecs r,k,v,g (one wave per row, unrolled vector loads), silu on g
//  k5 : per-head kv outer, wkv readout, state2 update (output 2),
//       instance-norm + affine + gate -> og
//  k6 : out0 = x + og @ Wo.T (output 0)

#define HDIM 4096
#define NHEAD 64
#define HSZ 64

#define WS_XL    0
#define WS_SX    4096
#define WS_XXX   8192
#define WS_PART  12288   // 16*320
#define WS_DPART 17408   // 16*128
#define WS_MV    20480   // 5*4096: f=0 mw, 1 mk, 2 mv, 3 mr, 4 mg
#define WS_TD    40960
#define WS_R     45056
#define WS_K     49152
#define WS_V     53248
#define WS_G     57344
#define WS_OG    61440
#define WS_FLAG  65536
// total 65537 floats ~= 256 KB of d_ws

typedef unsigned short bfraw;

__device__ __forceinline__ float bf2f(bfraw u) {
    union { unsigned int u; float f; } v; v.u = ((unsigned int)u) << 16; return v.f;
}
__device__ __forceinline__ bfraw f2bf(float f) {
    union { float f; unsigned int u; } v; v.f = f;
    unsigned int u = v.u;
    unsigned int r = (u + 0x7fffu + ((u >> 16) & 1u)) >> 16;  // RNE
    return (bfraw)r;
}
__device__ __forceinline__ float ldin(const void* p, long long i, bool isbf) {
    return isbf ? bf2f(((const bfraw*)p)[i]) : ((const float*)p)[i];
}
__device__ __forceinline__ void stout(void* p, long long i, float v, bool isbf) {
    if (isbf) ((bfraw*)p)[i] = f2bf(v); else ((float*)p)[i] = v;
}
__device__ __forceinline__ float waveReduce(float v) {
    for (int m = 32; m; m >>= 1) v += __shfl_xor(v, m);
    return v;
}

// ---------------- k0: detect dtype of input buffers ----------------------
// x is ~N(0,1). If bf16: slots 0..255 nearly all have sane exponents.
// If fp32-read-as-bf16: even slots are mantissa garbage -> cnt ~ 152 vs 256.
__global__ __launch_bounds__(64)
void k0_detect(const void* x, float* ws) {
    int lane = threadIdx.x;
    const bfraw* p = (const bfraw*)x;
    int cnt = 0;
    for (int k = 0; k < 4; ++k) {
        bfraw u = p[lane * 4 + k];
        int e = (u >> 7) & 0xFF;
        if (e >= 96 && e <= 144) cnt++;   // |v| in ~[2^-31, 2^17]
    }
    for (int m = 32; m; m >>= 1) cnt += __shfl_xor(cnt, m);
    if (lane == 0) ws[WS_FLAG] = (cnt >= 208) ? 1.0f : 0.0f;
}

// ---------------- k1: layernorm + token-shift mix input ----------------
__global__ __launch_bounds__(256)
void k1_ln_mix(const void* __restrict__ x, const void* __restrict__ st1,
               const void* __restrict__ lnw, const void* __restrict__ lnb,
               const void* __restrict__ tmx, void* __restrict__ dout,
               float* __restrict__ ws) {
    bool isbf = ws[WS_FLAG] != 0.0f;
    int tid = threadIdx.x;
    float xv[16];
    float s1 = 0.f, s2 = 0.f;
    for (int k = 0; k < 16; ++k) {
        float v = ldin(x, tid + k * 256, isbf);
        xv[k] = v; s1 += v; s2 += v * v;
    }
    s1 = waveReduce(s1); s2 = waveReduce(s2);
    __shared__ float red[8];
    int wid = tid >> 6, lane = tid & 63;
    if (lane == 0) { red[wid] = s1; red[4 + wid] = s2; }
    __syncthreads();
    float t1 = red[0] + red[1] + red[2] + red[3];
    float t2 = red[4] + red[5] + red[6] + red[7];
    float mu = t1 * (1.0f / HDIM);
    float var = fmaxf(t2 * (1.0f / HDIM) - mu * mu, 0.0f);
    float rstd = rsqrtf(var + 1e-5f);
    for (int k = 0; k < 16; ++k) {
        int i = tid + k * 256;
        float xl = (xv[k] - mu) * rstd * ldin(lnw, i, isbf) + ldin(lnb, i, isbf);
        float sx = ldin(st1, i, isbf) - xl;
        float xxx = xl + sx * ldin(tmx, i, isbf);
        stout(dout, 4096 + i, xl, isbf);   // output 1: xl
        ws[WS_XL + i] = xl;
        ws[WS_SX + i] = sx;
        ws[WS_XXX + i] = xxx;
    }
}

// ---------------- k2a: split-K partials of xxx @ maa_w1 (4096x320) -------
__global__ __launch_bounds__(320)
void k2a_maa_down(const void* __restrict__ w1, float* __restrict__ ws) {
    bool isbf = ws[WS_FLAG] != 0.0f;
    __shared__ float lx[256];
    int tid = threadIdx.x, b = blockIdx.x;
    if (tid < 256) lx[tid] = ws[WS_XXX + b * 256 + tid];
    __syncthreads();
    float acc = 0.f;
    long long base = (long long)b * 256 * 320 + tid;
    #pragma unroll 8
    for (int j = 0; j < 256; ++j) acc += lx[j] * ldin(w1, base + (long long)j * 320, isbf);
    ws[WS_PART + b * 320 + tid] = acc;
}

// ---------------- k2c: z=tanh(.), LoRA up, mvals -------------------------
__global__ __launch_bounds__(256)
void k2c_maa_up(const void* __restrict__ w2, const void* __restrict__ tm,
                float* __restrict__ ws) {
    bool isbf = ws[WS_FLAG] != 0.0f;
    int tid = threadIdx.x;
    int f = blockIdx.x >> 4;
    int hb = (blockIdx.x & 15) << 8;
    __shared__ float zl[64];
    if (tid < 64) {
        float s = 0.f;
        #pragma unroll
        for (int b = 0; b < 16; ++b) s += ws[WS_PART + b * 320 + f * 64 + tid];
        zl[tid] = tanhf(s);
    }
    __syncthreads();
    int h = hb + tid;
    float acc = 0.f;
    long long base = (long long)f * 64 * HDIM + h;
    #pragma unroll 8
    for (int t = 0; t < 64; ++t) acc += zl[t] * ldin(w2, base + (long long)t * HDIM, isbf);
    float mval = ws[WS_XL + h] + ws[WS_SX + h] * (acc + ldin(tm, f * HDIM + h, isbf));
    ws[WS_MV + f * HDIM + h] = mval;
}

// ---------------- k3a: split-K partials of mw @ decay_w1 (4096x128) ------
__global__ __launch_bounds__(128)
void k3a_decay_down(const void* __restrict__ dw1, float* __restrict__ ws) {
    bool isbf = ws[WS_FLAG] != 0.0f;
    __shared__ float lm[256];
    int tid = threadIdx.x, b = blockIdx.x;
    lm[tid]       = ws[WS_MV + b * 256 + tid];        // mw is f=0
    lm[tid + 128] = ws[WS_MV + b * 256 + 128 + tid];
    __syncthreads();
    float acc = 0.f;
    long long base = (long long)b * 256 * 128 + tid;
    #pragma unroll 8
    for (int j = 0; j < 256; ++j) acc += lm[j] * ldin(dw1, base + (long long)j * 128, isbf);
    ws[WS_DPART + b * 128 + tid] = acc;
}

// ---------------- k3b: dz=tanh(.), td = exp(-exp(clip(...))) -------------
__global__ __launch_bounds__(256)
void k3b_decay_up(const void* __restrict__ dw2, const void* __restrict__ tdec,
                  float* __restrict__ ws) {
    bool isbf = ws[WS_FLAG] != 0.0f;
    int tid = threadIdx.x;
    __shared__ float dz[128];
    if (tid < 128) {
        float s = 0.f;
        #pragma unroll
        for (int b = 0; b < 16; ++b) s += ws[WS_DPART + b * 128 + tid];
        dz[tid] = tanhf(s);
    }
    __syncthreads();
    int i = blockIdx.x * 256 + tid;
    float acc = 0.f;
    #pragma unroll 8
    for (int t = 0; t < 128; ++t) acc += dz[t] * ldin(dw2, (long long)t * HDIM + i, isbf);
    float tv = acc + ldin(tdec, i, isbf);
    tv = fminf(fmaxf(tv, -9.72f), 2.27f);
    ws[WS_TD + i] = expf(-expf(tv));
}

// ---------------- k4: 4 big matvecs r,k,v,g (one wave per row) -----------
__device__ __forceinline__ float dot_row_dual(const void* __restrict__ W, long long row,
                                              const float* __restrict__ m,
                                              int lane, bool isbf) {
    float acc = 0.f;
    if (isbf) {
        const bfraw* wr = (const bfraw*)W + row * HDIM;
        uint4 wv[8];
        #pragma unroll
        for (int it = 0; it < 8; ++it)
            wv[it] = *(const uint4*)(wr + it * 512 + lane * 8);
        #pragma unroll
        for (int it = 0; it < 8; ++it) {
            int base = it * 512 + lane * 8;
            float4 m0 = *(const float4*)(m + base);
            float4 m1 = *(const float4*)(m + base + 4);
            uint4 w4 = wv[it];
            acc += bf2f((bfraw)(w4.x & 0xffff)) * m0.x + bf2f((bfraw)(w4.x >> 16)) * m0.y;
            acc += bf2f((bfraw)(w4.y & 0xffff)) * m0.z + bf2f((bfraw)(w4.y >> 16)) * m0.w;
            acc += bf2f((bfraw)(w4.z & 0xffff)) * m1.x + bf2f((bfraw)(w4.z >> 16)) * m1.y;
            acc += bf2f((bfraw)(w4.w & 0xffff)) * m1.z + bf2f((bfraw)(w4.w >> 16)) * m1.w;
        }
    } else {
        const float* wr = (const float*)W + row * HDIM;
        float4 av[16];
        #pragma unroll
        for (int it = 0; it < 8; ++it) {
            av[2 * it]     = *(const float4*)(wr + it * 512 + lane * 8);
            av[2 * it + 1] = *(const float4*)(wr + it * 512 + lane * 8 + 4);
        }
        #pragma unroll
        for (int it = 0; it < 8; ++it) {
            int base = it * 512 + lane * 8;
            float4 m0 = *(const float4*)(m + base);
            float4 m1 = *(const float4*)(m + base + 4);
            float4 a0 = av[2 * it], a1 = av[2 * it + 1];
            acc += a0.x * m0.x + a0.y * m0.y + a0.z * m0.z + a0.w * m0.w;
            acc += a1.x * m1.x + a1.y * m1.y + a1.z * m1.z + a1.w * m1.w;
        }
    }
    return waveReduce(acc);
}

__global__ __launch_bounds__(256)
void k4_matvec4(const void* __restrict__ Wr, const void* __restrict__ Wk,
                const void* __restrict__ Wv, const void* __restrict__ Wg,
                float* __restrict__ ws) {
    bool isbf = ws[WS_FLAG] != 0.0f;
    int tid = threadIdx.x;
    int wave = tid >> 6, lane = tid & 63;
    int gr = blockIdx.x * 4 + wave;      // 0..16383
    int mat = gr >> 12;
    int row = gr & 4095;
    const void* W; const float* m; float* y;
    if (mat == 0)      { W = Wr; m = ws + WS_MV + 3 * HDIM; y = ws + WS_R; }
    else if (mat == 1) { W = Wk; m = ws + WS_MV + 1 * HDIM; y = ws + WS_K; }
    else if (mat == 2) { W = Wv; m = ws + WS_MV + 2 * HDIM; y = ws + WS_V; }
    else               { W = Wg; m = ws + WS_MV + 4 * HDIM; y = ws + WS_G; }
    float acc = dot_row_dual(W, row, m, lane, isbf);
    if (lane == 0) {
        if (mat == 3) acc = acc / (1.0f + expf(-acc));   // silu
        y[row] = acc;
    }
}

// ---------------- k5: per-head state update + readout + IN + gate --------
__global__ __launch_bounds__(64)
void k5_heads(const void* __restrict__ state2, const void* __restrict__ tfirst,
              const void* __restrict__ lnxw, const void* __restrict__ lnxb,
              void* __restrict__ dout, float* __restrict__ ws) {
    bool isbf = ws[WS_FLAG] != 0.0f;
    int h = blockIdx.x, j = threadIdx.x;
    int gi = h * 64 + j;
    float rj = ws[WS_R + gi], kj = ws[WS_K + gi], vj = ws[WS_V + gi];
    float tdj = ws[WS_TD + gi];
    float tfj = ldin(tfirst, gi, isbf);
    __shared__ float lr[64], lk[64], ltd[64];
    lr[j] = rj; lk[j] = kj; ltd[j] = tdj;
    float c = waveReduce(rj * kj * tfj);   // sum_i r_i k_i tf_i
    __syncthreads();
    float acc = 0.f;
    long long sbase = (long long)h * 4096 + j;
    #pragma unroll 8
    for (int i = 0; i < 64; ++i) {
        float s = ldin(state2, sbase + i * 64, isbf);
        acc += lr[i] * s;                                            // r @ state2 part
        stout(dout, 8192 + sbase + i * 64, lk[i] * vj + s * ltd[i], isbf);  // output 2
    }
    float oh = vj * c + acc;                            // r @ (kv*tf + s)
    float s1 = waveReduce(oh);
    float s2 = waveReduce(oh * oh);
    float mu = s1 * (1.0f / 64.0f);
    float var = fmaxf(s2 * (1.0f / 64.0f) - mu * mu, 0.0f);
    float rstd = rsqrtf(var + 1e-5f);
    float o = (oh - mu) * rstd * ldin(lnxw, gi, isbf) + ldin(lnxb, gi, isbf);
    ws[WS_OG + gi] = o * ws[WS_G + gi];
}

// ---------------- k6: out0 = x + og @ Wo.T -------------------------------
__global__ __launch_bounds__(256)
void k6_out(const void* __restrict__ Wo, const void* __restrict__ x,
            void* __restrict__ dout, float* __restrict__ ws) {
    bool isbf = ws[WS_FLAG] != 0.0f;
    int tid = threadIdx.x;
    int wave = tid >> 6, lane = tid & 63;
    int row = blockIdx.x * 4 + wave;
    float acc = dot_row_dual(Wo, row, ws + WS_OG, lane, isbf);
    if (lane == 0) stout(dout, row, ldin(x, row, isbf) + acc, isbf);
}

extern "C" void kernel_launch(void* const* d_in, const int* in_sizes, int n_in,
                              void* d_out, int out_size, void* d_ws, size_t ws_size,
                              hipStream_t stream) {
    const void* x      = d_in[0];
    const void* st1    = d_in[1];
    const void* st2    = d_in[2];
    const void* ln1w   = d_in[3];
    const void* ln1b   = d_in[4];
    const void* tmx    = d_in[5];
    const void* tmaa   = d_in[6];
    const void* maw1   = d_in[7];
    const void* maw2   = d_in[8];
    const void* tdec   = d_in[9];
    const void* tfirst = d_in[10];
    const void* dw1    = d_in[11];
    const void* dw2    = d_in[12];
    const void* Wr     = d_in[13];
    const void* Wk     = d_in[14];
    const void* Wv     = d_in[15];
    const void* Wg     = d_in[16];
    const void* Wo     = d_in[17];
    const void* lnxw   = d_in[18];
    const void* lnxb   = d_in[19];

    float* ws = (float*)d_ws;

    k0_detect<<<1, 64, 0, stream>>>(x, ws);
    k1_ln_mix<<<1, 256, 0, stream>>>(x, st1, ln1w, ln1b, tmx, d_out, ws);
    k2a_maa_down<<<16, 320, 0, stream>>>(maw1, ws);
    k2c_maa_up<<<80, 256, 0, stream>>>(maw2, tmaa, ws);
    k3a_decay_down<<<16, 128, 0, stream>>>(dw1, ws);
    k3b_decay_up<<<16, 256, 0, stream>>>(dw2, tdec, ws);
    k4_matvec4<<<4096, 256, 0, stream>>>(Wr, Wk, Wv, Wg, ws);
    k5_heads<<<64, 64, 0, stream>>>(st2, tfirst, lnxw, lnxb, d_out, ws);
    k6_out<<<1024, 256, 0, stream>>>(Wo, x, d_out, ws);
}